// Round 16
// baseline (927.236 us; speedup 1.0000x reference)
//
#include <hip/hip_runtime.h>
#include <hip/hip_fp16.h>

#define N_NODES  100000
#define N_EDGES  1600000
#define N_GRAPHS 64

#define BINSH  8
#define NBIN   392          // bins of 256 nodes (last ones empty-guarded)
#define BINCAP 5120         // Poisson(4081) max ~4.4K; safe headroom
#define EPB    4096         // edges per block in k_binA (1024 threads x 4)

typedef _Float16 half8 __attribute__((ext_vector_type(8)));
typedef float float4v __attribute__((ext_vector_type(4)));

__device__ __forceinline__ float lrelu(float v) { return v > 0.f ? v : 0.2f * v; }
__device__ __forceinline__ float elu_f(float v) { return v > 0.f ? v : __expf(v) - 1.f; }

// ---- Pass A: coarse-bin edges (dst>>8) into per-bin regions, coalesced runs.
// 1024 threads x 4096 edges (391 blocks): half the per-block fixed cost of
// the 782x512 config. binned entries packed: (dst_local << 17) | src.
__global__ __launch_bounds__(1024) void k_binA(
    const int* __restrict__ src, const int* __restrict__ dst,
    const int* __restrict__ batch, int* __restrict__ gbin_cursor,
    int* __restrict__ cnt, int* __restrict__ binned) {
    __shared__ int hist[NBIN], lexcl[NBIN], runbase[NBIN], lcur[NBIN];
    __shared__ int wpart[16];
    __shared__ int gh[N_GRAPHS];
    __shared__ int2 stage[EPB];   // {packed, bin}  32 KB
    int t = threadIdx.x;
    int e0 = blockIdx.x * EPB;
    for (int b = t; b < NBIN; b += 1024) hist[b] = 0;
    if (t < N_GRAPHS) gh[t] = 0;
    __syncthreads();
    int nid = blockIdx.x * 1024 + t;   // 391*1024 >= N_NODES
    if (nid < N_NODES) atomicAdd(&gh[batch[nid]], 1);
    int e = 4 * t;
    int4 dv = make_int4(0, 0, 0, 0), sv = make_int4(0, 0, 0, 0);
    bool full = (e0 + e + 3 < N_EDGES);
    if (full) {
        dv = *(const int4*)(dst + e0 + e);
        sv = *(const int4*)(src + e0 + e);
        atomicAdd(&hist[dv.x >> BINSH], 1);
        atomicAdd(&hist[dv.y >> BINSH], 1);
        atomicAdd(&hist[dv.z >> BINSH], 1);
        atomicAdd(&hist[dv.w >> BINSH], 1);
    } else {
        for (int k = 0; k < 4; ++k)
            if (e0 + e + k < N_EDGES) atomicAdd(&hist[dst[e0 + e + k] >> BINSH], 1);
    }
    __syncthreads();
    int v = (t < NBIN) ? hist[t] : 0;
    int x = v;
#pragma unroll
    for (int d = 1; d < 64; d <<= 1) {
        int y = __shfl_up(x, d, 64);
        if ((t & 63) >= d) x += y;
    }
    if ((t & 63) == 63) wpart[t >> 6] = x;
    __syncthreads();
    if (t == 0) {
        int a = 0;
        for (int w = 0; w < 16; ++w) { int q = wpart[w]; wpart[w] = a; a += q; }
    }
    __syncthreads();
    int excl = x - v + wpart[t >> 6];
    if (t < NBIN) { lexcl[t] = excl; lcur[t] = excl; }
    __syncthreads();
    if (t < NBIN && v > 0) runbase[t] = atomicAdd(&gbin_cursor[t], v);
    if (t < N_GRAPHS && gh[t]) atomicAdd(&cnt[t], gh[t]);
    __syncthreads();
    if (full) {
        int p, b_;
        b_ = dv.x >> BINSH; p = atomicAdd(&lcur[b_], 1);
        stage[p] = make_int2(((dv.x & 255) << 17) | sv.x, b_);
        b_ = dv.y >> BINSH; p = atomicAdd(&lcur[b_], 1);
        stage[p] = make_int2(((dv.y & 255) << 17) | sv.y, b_);
        b_ = dv.z >> BINSH; p = atomicAdd(&lcur[b_], 1);
        stage[p] = make_int2(((dv.z & 255) << 17) | sv.z, b_);
        b_ = dv.w >> BINSH; p = atomicAdd(&lcur[b_], 1);
        stage[p] = make_int2(((dv.w & 255) << 17) | sv.w, b_);
    } else {
        for (int k = 0; k < 4; ++k) {
            if (e0 + e + k < N_EDGES) {
                int d = dst[e0 + e + k];
                int b_ = d >> BINSH;
                int p = atomicAdd(&lcur[b_], 1);
                stage[p] = make_int2(((d & 255) << 17) | src[e0 + e + k], b_);
            }
        }
    }
    __syncthreads();
    int m = N_EDGES - e0;
    if (m > EPB) m = EPB;
    for (int i = 4 * t; i < 4 * t + 4 && i < m; ++i) {
        int2 pr = stage[i];
        int b_ = pr.y;
        binned[(size_t)b_ * BINCAP + runbase[b_] + (i - lexcl[b_])] = pr.x;
    }
}

// ---- MEGA pass B (R15-proven): counting sort -> off/csr, then IN-BLOCK:
// layer-1 (shuffle-reduce, no atomics), exact-fp32 logits, MFMA h2 GEMM.
__global__ __launch_bounds__(1024) void k_megaB(
    const int* __restrict__ binned, const int* __restrict__ gbin_cursor,
    int* __restrict__ off, int* __restrict__ csr,
    const float* __restrict__ x, const float* __restrict__ W1,
    const float* __restrict__ as1, const float* __restrict__ ad1,
    const float* __restrict__ b1, const float* __restrict__ W2,
    const float* __restrict__ as2, const float* __restrict__ ad2,
    __half2* __restrict__ h2p, float2* __restrict__ ap, float2* __restrict__ dp) {
    __shared__ int hist[256], lstart[256];
    __shared__ int wpart[4];
    __shared__ int s_ebase;
    __shared__ float s1l[256 * 8];
    __shared__ float smWs[512], smWd[512];
    __shared__ float smW1[64], smB1[64];
    __shared__ float ws8s[8], wd8s[8];
    __shared__ _Float16 smWT[128 * 72];
    __shared__ _Float16 smA[256 * 72];
    int b = blockIdx.x, t = threadIdx.x;
    int count = gbin_cursor[b];
    int node0 = b << BINSH;
    const int* my = binned + (size_t)b * BINCAP;

    if (t == 0) s_ebase = 0;
    if (t < 256) hist[t] = 0;
    for (int idx = t; idx < 8192; idx += 1024) {
        int c = idx >> 6, k = idx & 63;
        smWT[c * 72 + k] = (_Float16)W2[k * 128 + c];
    }
    {
        int tt = t & 511;
        int k = tt >> 3, h = tt & 7;
        const float* att = (t < 512) ? as2 : ad2;
        float acc = 0.f;
        for (int c = 0; c < 16; ++c)
            acc += W2[k * 128 + h * 16 + c] * att[h * 16 + c];
        if (t < 512) smWs[k * 8 + h] = acc; else smWd[k * 8 + h] = acc;
    }
    if (t < 64) { smW1[t] = W1[t]; smB1[t] = b1[t]; }
    if (t >= 64 && t < 72) {
        int h = t - 64;
        float s = 0.f, d = 0.f;
        for (int c = 0; c < 8; ++c) {
            float w = W1[h * 8 + c];
            s += w * as1[h * 8 + c];
            d += w * ad1[h * 8 + c];
        }
        ws8s[h] = s;
        wd8s[h] = d;
    }
    __syncthreads();

    if (t < b) atomicAdd(&s_ebase, gbin_cursor[t]);
    for (int i = t; i < count; i += 1024) atomicAdd(&hist[my[i] >> 17], 1);
    __syncthreads();

    int v = (t < 256) ? hist[t] : 0;
    int xx = v;
#pragma unroll
    for (int d = 1; d < 64; d <<= 1) {
        int y = __shfl_up(xx, d, 64);
        if ((t & 63) >= d) xx += y;
    }
    if (t < 256 && (t & 63) == 63) wpart[t >> 6] = xx;
    __syncthreads();
    if (t == 0) {
        int a = 0;
        for (int w = 0; w < 4; ++w) { int q = wpart[w]; wpart[w] = a; a += q; }
    }
    __syncthreads();
    int ebase = s_ebase;
    int excl = xx - v + ((t < 256) ? wpart[t >> 6] : 0);
    if (t < 256) {
        int n = node0 + t;
        if (n < N_NODES) off[n] = ebase + excl;
        lstart[t] = excl;
        hist[t] = excl;    // cursor
    }
    if (b == 0 && t == 0) off[N_NODES] = N_EDGES;
    __syncthreads();

    for (int i = t; i < count; i += 1024) {
        int pr = my[i];
        int p = atomicAdd(&hist[pr >> 17], 1);
        csr[ebase + p] = pr & 0x1FFFF;
    }
    __syncthreads();

    // layer 1: 4 lanes/node shuffle-reduce
    {
        int nl = t >> 2, c = t & 3;
        int n = node0 + nl;
        float ws[8], wd[8];
#pragma unroll
        for (int h = 0; h < 8; ++h) { ws[h] = ws8s[h]; wd[h] = wd8s[h]; }
        float xn = (n < N_NODES) ? x[n] : 0.f;
        float num[8], den[8];
#pragma unroll
        for (int h = 0; h < 8; ++h) { num[h] = 0.f; den[h] = 0.f; }
        if (c == 0 && n < N_NODES) {
#pragma unroll
            for (int h = 0; h < 8; ++h) {
                float w = __expf(lrelu(xn * ws[h] + xn * wd[h]));
                den[h] = w;
                num[h] = w * xn;
            }
        }
        int st = lstart[nl], en = hist[nl];
        for (int j = st + c; j < en; j += 4) {
            int s = csr[ebase + j];
            float xs = x[s];
#pragma unroll
            for (int h = 0; h < 8; ++h) {
                float w = __expf(lrelu(xs * ws[h] + xn * wd[h]));
                den[h] += w;
                num[h] += w * xs;
            }
        }
#pragma unroll
        for (int d = 1; d < 4; d <<= 1) {
#pragma unroll
            for (int h = 0; h < 8; ++h) {
                num[h] += __shfl_xor(num[h], d, 64);
                den[h] += __shfl_xor(den[h], d, 64);
            }
        }
        if (c == 0) {
#pragma unroll
            for (int h = 0; h < 8; ++h)
                s1l[nl * 8 + h] = (n < N_NODES) ? num[h] / den[h] : 0.f;
        }
    }
    __syncthreads();

    // exact-fp32 logits + smA fill
    {
        int nl = t >> 2, j = t & 3;
        int n = node0 + nl;
        if (n < N_NODES) {
            float pSA = 0.f, pSB = 0.f, pDA = 0.f, pDB = 0.f;
#pragma unroll 8
            for (int k = 0; k < 64; ++k) {
                float h1a = elu_f(s1l[nl * 8 + (k >> 3)] * smW1[k] + smB1[k]);
                pSA += h1a * smWs[k * 8 + j];
                pSB += h1a * smWs[k * 8 + j + 4];
                pDA += h1a * smWd[k * 8 + j];
                pDB += h1a * smWd[k * 8 + j + 4];
            }
            ap[n * 4 + j] = make_float2(pSA, pSB);
            dp[n * 4 + j] = make_float2(pDA, pDB);
        }
    }
    for (int i = t; i < 256 * 64; i += 1024) {
        int m = i >> 6, k = i & 63;
        smA[m * 72 + k] = (_Float16)elu_f(s1l[m * 8 + (k >> 3)] * smW1[k] + smB1[k]);
    }
    __syncthreads();

    // MFMA h2 GEMM, 16 waves x 16 nodes
    {
        int wave = t >> 6, lane = t & 63;
        int quad = lane >> 4, m15 = lane & 15;
        half8 a0 = *reinterpret_cast<const half8*>(&smA[(wave * 16 + m15) * 72 + quad * 8]);
        half8 a1 = *reinterpret_cast<const half8*>(&smA[(wave * 16 + m15) * 72 + 32 + quad * 8]);
        float4v acc[8];
#pragma unroll
        for (int tl = 0; tl < 8; ++tl) {
            half8 b0 = *reinterpret_cast<const half8*>(&smWT[(tl * 16 + m15) * 72 + quad * 8]);
            half8 b1v = *reinterpret_cast<const half8*>(&smWT[(tl * 16 + m15) * 72 + 32 + quad * 8]);
            float4v c = {0.f, 0.f, 0.f, 0.f};
            c = __builtin_amdgcn_mfma_f32_16x16x32_f16(a0, b0, c, 0, 0, 0);
            c = __builtin_amdgcn_mfma_f32_16x16x32_f16(a1, b1v, c, 0, 0, 0);
            acc[tl] = c;
        }
#pragma unroll
        for (int tl = 0; tl < 4; ++tl) {
#pragma unroll
            for (int reg = 0; reg < 4; ++reg) {
                int n = node0 + wave * 16 + quad * 4 + reg;
                if (n < N_NODES)
                    h2p[n * 64 + tl * 16 + m15] =
                        __floats2half2_rn(acc[tl][reg], acc[tl + 4][reg]);
            }
        }
    }
}

// ---- Layer 2 aggregation (frozen R10 gather structure, ~110us) with the
// FINAL kernel fused in via a device-scope done-counter: the last block
// re-reads pool through atomic reads and writes the [64,4] output.
__global__ __launch_bounds__(256, 8) void k_layer2(
    const __half2* __restrict__ h2p, const float2* __restrict__ ap,
    const float2* __restrict__ dp, const int* __restrict__ off,
    const int* __restrict__ csr, const int* __restrict__ batch,
    float* __restrict__ pool, int* __restrict__ done,
    const int* __restrict__ cnt, const float* __restrict__ b2,
    const float* __restrict__ Wfc, const float* __restrict__ bfc,
    float* __restrict__ out) {
    __shared__ float smv[4][16];
    __shared__ int smg[4];
    __shared__ int s_last;
    const float* apf = (const float*)ap;   // flat: node*8 + 2*(h&3) + (h>>2)
    const float* dpf = (const float*)dp;
    int t = threadIdx.x;
    int wid = t >> 6, l = t & 63;
    int n = blockIdx.x * 4 + wid;  // grid exact: 25000*4 == N_NODES
    int hA = l >> 4;
    int hh = l & 7;
    int j8 = l >> 3;
    int fidx = 2 * (hh & 3) + (hh >> 2);
    float dn = dpf[n * 8 + fidx];

    float2 ad = dp[n * 4 + hA];
    float2 an = ap[n * 4 + hA];
    float wA = __expf(lrelu(an.x + ad.x));
    float wB = __expf(lrelu(an.y + ad.y));
    float2 hn = __half22float2(h2p[n * 64 + l]);
    float accA = wA * hn.x, accB = wB * hn.y;
    float denTA = wA, denTB = wB;
    float wsum = 0.f;

    int b = off[n];
    int deg = off[n + 1] - b;
    for (int base = 0; base < deg; base += 64) {
        int rem = deg - base;
        if (rem > 64) rem = 64;
        int sl = (l < rem) ? csr[b + base + l] : 0;
        int g = 0;
        for (; g + 8 <= rem; g += 8) {
            int sg = __shfl(sl, g + j8, 64);
            float w = __expf(lrelu(apf[sg * 8 + fidx] + dn));
            wsum += w;
#pragma unroll
            for (int j2 = 0; j2 < 8; ++j2) {
                int s = __builtin_amdgcn_readlane(sl, g + j2);
                float wa = __shfl(w, j2 * 8 + hA, 64);
                float wb = __shfl(w, j2 * 8 + hA + 4, 64);
                float2 gg = __half22float2(h2p[s * 64 + l]);
                accA = fmaf(wa, gg.x, accA);
                accB = fmaf(wb, gg.y, accB);
            }
        }
        if (g < rem) {
            int cnt2 = rem - g;
            int jj = (j8 < cnt2) ? j8 : 0;
            int sg = __shfl(sl, g + jj, 64);
            float w = (j8 < cnt2) ? __expf(lrelu(apf[sg * 8 + fidx] + dn)) : 0.f;
            wsum += w;
            for (int j2 = 0; j2 < cnt2; ++j2) {
                int s = __builtin_amdgcn_readlane(sl, g + j2);
                float wa = __shfl(w, j2 * 8 + hA, 64);
                float wb = __shfl(w, j2 * 8 + hA + 4, 64);
                float2 gg = __half22float2(h2p[s * 64 + l]);
                accA = fmaf(wa, gg.x, accA);
                accB = fmaf(wb, gg.y, accB);
            }
        }
    }
    wsum += __shfl_xor(wsum, 8, 64);
    wsum += __shfl_xor(wsum, 16, 64);
    wsum += __shfl_xor(wsum, 32, 64);
    float denA = denTA + __shfl(wsum, hA, 64);
    float denB = denTB + __shfl(wsum, hA + 4, 64);

    float v = accA / denA + accB / denB;
    v += __shfl_xor(v, 16, 64);
    v += __shfl_xor(v, 32, 64);
    v *= 0.125f;
    if (l < 16) smv[wid][l] = v;
    if (l == 0) smg[wid] = batch[n];
    __syncthreads();
    if (t < 64) {
        int w = t >> 4, c = t & 15;
        int g = smg[w];
        bool leader = true;
        for (int w2 = 0; w2 < w; ++w2)
            if (smg[w2] == g) { leader = false; break; }
        if (leader) {
            float s = smv[w][c];
            for (int w2 = w + 1; w2 < 4; ++w2)
                if (smg[w2] == g) s += smv[w2][c];
            atomicAdd(&pool[g * 16 + c], s);
        }
    }
    __syncthreads();
    // ---- fused final: last block computes pooled mean @ Wfc + bfc
    if (t == 0) {
        __threadfence();
        int r = atomicAdd(done, 1);
        s_last = (r == (int)gridDim.x - 1) ? 1 : 0;
    }
    __syncthreads();
    if (s_last) {
        __threadfence();
        int g = t >> 2, k = t & 3;
        float c = (float)(cnt[g] > 0 ? cnt[g] : 1);
        float acc = bfc[k];
#pragma unroll
        for (int ci = 0; ci < 16; ++ci) {
            float pv = atomicAdd(&pool[g * 16 + ci], 0.f);  // coherent L2 read
            acc += (pv / c + b2[ci]) * Wfc[ci * 4 + k];
        }
        out[g * 4 + k] = acc;
    }
}

extern "C" void kernel_launch(void* const* d_in, const int* in_sizes, int n_in,
                              void* d_out, int out_size, void* d_ws, size_t ws_size,
                              hipStream_t stream) {
    const float* x   = (const float*)d_in[0];
    const float* W1  = (const float*)d_in[1];
    const float* as1 = (const float*)d_in[2];
    const float* ad1 = (const float*)d_in[3];
    const float* b1  = (const float*)d_in[4];
    const float* W2  = (const float*)d_in[5];
    const float* as2 = (const float*)d_in[6];
    const float* ad2 = (const float*)d_in[7];
    const float* b2  = (const float*)d_in[8];
    const float* Wfc = (const float*)d_in[9];
    const float* bfc = (const float*)d_in[10];
    const int* ei    = (const int*)d_in[11];
    const int* batch = (const int*)d_in[12];
    const int* srcv  = ei;             // edge_index[0]
    const int* dstv  = ei + N_EDGES;   // edge_index[1]

    char* ws = (char*)d_ws;
    size_t o = 0;
    auto alloc = [&](size_t bytes) {
        void* p = ws + o;
        o += (bytes + 255) & ~(size_t)255;
        return p;
    };
    // zero-region first (one memset): cnt, pool, gbin_cursor, done
    int*    cnt     = (int*)alloc(64 * 4);
    float*  pool    = (float*)alloc(64 * 16 * 4);
    int*    gbin    = (int*)alloc(NBIN * 4);
    int*    done    = (int*)alloc(4);
    size_t  zbytes  = o;
    int*    off     = (int*)alloc((size_t)(N_NODES + 1) * 4);
    int*    csr     = (int*)alloc((size_t)N_EDGES * 4);
    float2* ap      = (float2*)alloc((size_t)N_NODES * 4 * 8);
    float2* dp      = (float2*)alloc((size_t)N_NODES * 4 * 8);
    int*    binned  = (int*)alloc((size_t)NBIN * BINCAP * 4);    // 8.0 MB packed
    __half2* h2p    = (__half2*)alloc((size_t)N_NODES * 64 * 4); // 25.6 MB

    hipMemsetAsync(d_ws, 0, zbytes, stream);

    int nbA = (N_EDGES + EPB - 1) / EPB;   // 391

    k_binA<<<nbA, 1024, 0, stream>>>(srcv, dstv, batch, gbin, cnt, binned);
    k_megaB<<<NBIN, 1024, 0, stream>>>(binned, gbin, off, csr,
                                       x, W1, as1, ad1, b1, W2, as2, ad2,
                                       h2p, ap, dp);
    k_layer2<<<N_NODES / 4, 256, 0, stream>>>(h2p, ap, dp, off, csr, batch,
                                              pool, done, cnt, b2, Wfc, bfc,
                                              (float*)d_out);
}

// Round 17
// 264.141 us; speedup vs baseline: 3.5104x; 3.5104x over previous
//
#include <hip/hip_runtime.h>
#include <hip/hip_fp16.h>

#define N_NODES  100000
#define N_EDGES  1600000
#define N_GRAPHS 64

#define BINSH  8
#define NBIN   392          // bins of 256 nodes (last ones empty-guarded)
#define BINCAP 5120         // Poisson(4081) max ~4.4K; safe headroom
#define EPB    4096         // edges per block in k_binA (1024 threads x 4)

typedef _Float16 half8 __attribute__((ext_vector_type(8)));
typedef float float4v __attribute__((ext_vector_type(4)));

__device__ __forceinline__ float lrelu(float v) { return v > 0.f ? v : 0.2f * v; }
__device__ __forceinline__ float elu_f(float v) { return v > 0.f ? v : __expf(v) - 1.f; }

// ---- Pass A: coarse-bin edges (dst>>8) into per-bin regions, coalesced runs.
// binned entries packed: (dst_local << 17) | src.
__global__ __launch_bounds__(1024) void k_binA(
    const int* __restrict__ src, const int* __restrict__ dst,
    const int* __restrict__ batch, int* __restrict__ gbin_cursor,
    int* __restrict__ cnt, int* __restrict__ binned) {
    __shared__ int hist[NBIN], lexcl[NBIN], runbase[NBIN], lcur[NBIN];
    __shared__ int wpart[16];
    __shared__ int gh[N_GRAPHS];
    __shared__ int2 stage[EPB];   // {packed, bin}  32 KB
    int t = threadIdx.x;
    int e0 = blockIdx.x * EPB;
    for (int b = t; b < NBIN; b += 1024) hist[b] = 0;
    if (t < N_GRAPHS) gh[t] = 0;
    __syncthreads();
    int nid = blockIdx.x * 1024 + t;   // 391*1024 >= N_NODES
    if (nid < N_NODES) atomicAdd(&gh[batch[nid]], 1);
    int e = 4 * t;
    int4 dv = make_int4(0, 0, 0, 0), sv = make_int4(0, 0, 0, 0);
    bool full = (e0 + e + 3 < N_EDGES);
    if (full) {
        dv = *(const int4*)(dst + e0 + e);
        sv = *(const int4*)(src + e0 + e);
        atomicAdd(&hist[dv.x >> BINSH], 1);
        atomicAdd(&hist[dv.y >> BINSH], 1);
        atomicAdd(&hist[dv.z >> BINSH], 1);
        atomicAdd(&hist[dv.w >> BINSH], 1);
    } else {
        for (int k = 0; k < 4; ++k)
            if (e0 + e + k < N_EDGES) atomicAdd(&hist[dst[e0 + e + k] >> BINSH], 1);
    }
    __syncthreads();
    int v = (t < NBIN) ? hist[t] : 0;
    int x = v;
#pragma unroll
    for (int d = 1; d < 64; d <<= 1) {
        int y = __shfl_up(x, d, 64);
        if ((t & 63) >= d) x += y;
    }
    if ((t & 63) == 63) wpart[t >> 6] = x;
    __syncthreads();
    if (t == 0) {
        int a = 0;
        for (int w = 0; w < 16; ++w) { int q = wpart[w]; wpart[w] = a; a += q; }
    }
    __syncthreads();
    int excl = x - v + wpart[t >> 6];
    if (t < NBIN) { lexcl[t] = excl; lcur[t] = excl; }
    __syncthreads();
    if (t < NBIN && v > 0) runbase[t] = atomicAdd(&gbin_cursor[t], v);
    if (t < N_GRAPHS && gh[t]) atomicAdd(&cnt[t], gh[t]);
    __syncthreads();
    if (full) {
        int p, b_;
        b_ = dv.x >> BINSH; p = atomicAdd(&lcur[b_], 1);
        stage[p] = make_int2(((dv.x & 255) << 17) | sv.x, b_);
        b_ = dv.y >> BINSH; p = atomicAdd(&lcur[b_], 1);
        stage[p] = make_int2(((dv.y & 255) << 17) | sv.y, b_);
        b_ = dv.z >> BINSH; p = atomicAdd(&lcur[b_], 1);
        stage[p] = make_int2(((dv.z & 255) << 17) | sv.z, b_);
        b_ = dv.w >> BINSH; p = atomicAdd(&lcur[b_], 1);
        stage[p] = make_int2(((dv.w & 255) << 17) | sv.w, b_);
    } else {
        for (int k = 0; k < 4; ++k) {
            if (e0 + e + k < N_EDGES) {
                int d = dst[e0 + e + k];
                int b_ = d >> BINSH;
                int p = atomicAdd(&lcur[b_], 1);
                stage[p] = make_int2(((d & 255) << 17) | src[e0 + e + k], b_);
            }
        }
    }
    __syncthreads();
    int m = N_EDGES - e0;
    if (m > EPB) m = EPB;
    for (int i = 4 * t; i < 4 * t + 4 && i < m; ++i) {
        int2 pr = stage[i];
        int b_ = pr.y;
        binned[(size_t)b_ * BINCAP + runbase[b_] + (i - lexcl[b_])] = pr.x;
    }
}

// ---- MEGA pass B (R15-proven): counting sort -> off/csr, then IN-BLOCK:
// layer-1 (shuffle-reduce, no atomics), exact-fp32 logits, MFMA h2 GEMM.
__global__ __launch_bounds__(1024) void k_megaB(
    const int* __restrict__ binned, const int* __restrict__ gbin_cursor,
    int* __restrict__ off, int* __restrict__ csr,
    const float* __restrict__ x, const float* __restrict__ W1,
    const float* __restrict__ as1, const float* __restrict__ ad1,
    const float* __restrict__ b1, const float* __restrict__ W2,
    const float* __restrict__ as2, const float* __restrict__ ad2,
    __half2* __restrict__ h2p, float2* __restrict__ ap, float2* __restrict__ dp) {
    __shared__ int hist[256], lstart[256];
    __shared__ int wpart[4];
    __shared__ int s_ebase;
    __shared__ float s1l[256 * 8];
    __shared__ float smWs[512], smWd[512];
    __shared__ float smW1[64], smB1[64];
    __shared__ float ws8s[8], wd8s[8];
    __shared__ _Float16 smWT[128 * 72];
    __shared__ _Float16 smA[256 * 72];
    int b = blockIdx.x, t = threadIdx.x;
    int count = gbin_cursor[b];
    int node0 = b << BINSH;
    const int* my = binned + (size_t)b * BINCAP;

    if (t == 0) s_ebase = 0;
    if (t < 256) hist[t] = 0;
    for (int idx = t; idx < 8192; idx += 1024) {
        int c = idx >> 6, k = idx & 63;
        smWT[c * 72 + k] = (_Float16)W2[k * 128 + c];
    }
    {
        int tt = t & 511;
        int k = tt >> 3, h = tt & 7;
        const float* att = (t < 512) ? as2 : ad2;
        float acc = 0.f;
        for (int c = 0; c < 16; ++c)
            acc += W2[k * 128 + h * 16 + c] * att[h * 16 + c];
        if (t < 512) smWs[k * 8 + h] = acc; else smWd[k * 8 + h] = acc;
    }
    if (t < 64) { smW1[t] = W1[t]; smB1[t] = b1[t]; }
    if (t >= 64 && t < 72) {
        int h = t - 64;
        float s = 0.f, d = 0.f;
        for (int c = 0; c < 8; ++c) {
            float w = W1[h * 8 + c];
            s += w * as1[h * 8 + c];
            d += w * ad1[h * 8 + c];
        }
        ws8s[h] = s;
        wd8s[h] = d;
    }
    __syncthreads();

    if (t < b) atomicAdd(&s_ebase, gbin_cursor[t]);
    for (int i = t; i < count; i += 1024) atomicAdd(&hist[my[i] >> 17], 1);
    __syncthreads();

    int v = (t < 256) ? hist[t] : 0;
    int xx = v;
#pragma unroll
    for (int d = 1; d < 64; d <<= 1) {
        int y = __shfl_up(xx, d, 64);
        if ((t & 63) >= d) xx += y;
    }
    if (t < 256 && (t & 63) == 63) wpart[t >> 6] = xx;
    __syncthreads();
    if (t == 0) {
        int a = 0;
        for (int w = 0; w < 4; ++w) { int q = wpart[w]; wpart[w] = a; a += q; }
    }
    __syncthreads();
    int ebase = s_ebase;
    int excl = xx - v + ((t < 256) ? wpart[t >> 6] : 0);
    if (t < 256) {
        int n = node0 + t;
        if (n < N_NODES) off[n] = ebase + excl;
        lstart[t] = excl;
        hist[t] = excl;    // cursor
    }
    if (b == 0 && t == 0) off[N_NODES] = N_EDGES;
    __syncthreads();

    for (int i = t; i < count; i += 1024) {
        int pr = my[i];
        int p = atomicAdd(&hist[pr >> 17], 1);
        csr[ebase + p] = pr & 0x1FFFF;
    }
    __syncthreads();

    // layer 1: 4 lanes/node shuffle-reduce
    {
        int nl = t >> 2, c = t & 3;
        int n = node0 + nl;
        float ws[8], wd[8];
#pragma unroll
        for (int h = 0; h < 8; ++h) { ws[h] = ws8s[h]; wd[h] = wd8s[h]; }
        float xn = (n < N_NODES) ? x[n] : 0.f;
        float num[8], den[8];
#pragma unroll
        for (int h = 0; h < 8; ++h) { num[h] = 0.f; den[h] = 0.f; }
        if (c == 0 && n < N_NODES) {
#pragma unroll
            for (int h = 0; h < 8; ++h) {
                float w = __expf(lrelu(xn * ws[h] + xn * wd[h]));
                den[h] = w;
                num[h] = w * xn;
            }
        }
        int st = lstart[nl], en = hist[nl];
        for (int j = st + c; j < en; j += 4) {
            int s = csr[ebase + j];
            float xs = x[s];
#pragma unroll
            for (int h = 0; h < 8; ++h) {
                float w = __expf(lrelu(xs * ws[h] + xn * wd[h]));
                den[h] += w;
                num[h] += w * xs;
            }
        }
#pragma unroll
        for (int d = 1; d < 4; d <<= 1) {
#pragma unroll
            for (int h = 0; h < 8; ++h) {
                num[h] += __shfl_xor(num[h], d, 64);
                den[h] += __shfl_xor(den[h], d, 64);
            }
        }
        if (c == 0) {
#pragma unroll
            for (int h = 0; h < 8; ++h)
                s1l[nl * 8 + h] = (n < N_NODES) ? num[h] / den[h] : 0.f;
        }
    }
    __syncthreads();

    // exact-fp32 logits + smA fill
    {
        int nl = t >> 2, j = t & 3;
        int n = node0 + nl;
        if (n < N_NODES) {
            float pSA = 0.f, pSB = 0.f, pDA = 0.f, pDB = 0.f;
#pragma unroll 8
            for (int k = 0; k < 64; ++k) {
                float h1a = elu_f(s1l[nl * 8 + (k >> 3)] * smW1[k] + smB1[k]);
                pSA += h1a * smWs[k * 8 + j];
                pSB += h1a * smWs[k * 8 + j + 4];
                pDA += h1a * smWd[k * 8 + j];
                pDB += h1a * smWd[k * 8 + j + 4];
            }
            ap[n * 4 + j] = make_float2(pSA, pSB);
            dp[n * 4 + j] = make_float2(pDA, pDB);
        }
    }
    for (int i = t; i < 256 * 64; i += 1024) {
        int m = i >> 6, k = i & 63;
        smA[m * 72 + k] = (_Float16)elu_f(s1l[m * 8 + (k >> 3)] * smW1[k] + smB1[k]);
    }
    __syncthreads();

    // MFMA h2 GEMM, 16 waves x 16 nodes
    {
        int wave = t >> 6, lane = t & 63;
        int quad = lane >> 4, m15 = lane & 15;
        half8 a0 = *reinterpret_cast<const half8*>(&smA[(wave * 16 + m15) * 72 + quad * 8]);
        half8 a1 = *reinterpret_cast<const half8*>(&smA[(wave * 16 + m15) * 72 + 32 + quad * 8]);
        float4v acc[8];
#pragma unroll
        for (int tl = 0; tl < 8; ++tl) {
            half8 b0 = *reinterpret_cast<const half8*>(&smWT[(tl * 16 + m15) * 72 + quad * 8]);
            half8 b1v = *reinterpret_cast<const half8*>(&smWT[(tl * 16 + m15) * 72 + 32 + quad * 8]);
            float4v c = {0.f, 0.f, 0.f, 0.f};
            c = __builtin_amdgcn_mfma_f32_16x16x32_f16(a0, b0, c, 0, 0, 0);
            c = __builtin_amdgcn_mfma_f32_16x16x32_f16(a1, b1v, c, 0, 0, 0);
            acc[tl] = c;
        }
#pragma unroll
        for (int tl = 0; tl < 4; ++tl) {
#pragma unroll
            for (int reg = 0; reg < 4; ++reg) {
                int n = node0 + wave * 16 + quad * 4 + reg;
                if (n < N_NODES)
                    h2p[n * 64 + tl * 16 + m15] =
                        __floats2half2_rn(acc[tl][reg], acc[tl + 4][reg]);
            }
        }
    }
}

// ---- Layer 2 aggregation: frozen R10/R15 gather structure (~110us).
// NO device-scope fence / done-counter here — R16 proved a per-block
// __threadfence costs ~670us by stalling the whole gather pipeline.
__global__ __launch_bounds__(256, 8) void k_layer2(
    const __half2* __restrict__ h2p, const float2* __restrict__ ap,
    const float2* __restrict__ dp, const int* __restrict__ off,
    const int* __restrict__ csr, const int* __restrict__ batch,
    float* __restrict__ pool) {
    __shared__ float smv[4][16];
    __shared__ int smg[4];
    const float* apf = (const float*)ap;   // flat: node*8 + 2*(h&3) + (h>>2)
    const float* dpf = (const float*)dp;
    int t = threadIdx.x;
    int wid = t >> 6, l = t & 63;
    int n = blockIdx.x * 4 + wid;  // grid exact: 25000*4 == N_NODES
    int hA = l >> 4;
    int hh = l & 7;
    int j8 = l >> 3;
    int fidx = 2 * (hh & 3) + (hh >> 2);
    float dn = dpf[n * 8 + fidx];

    float2 ad = dp[n * 4 + hA];
    float2 an = ap[n * 4 + hA];
    float wA = __expf(lrelu(an.x + ad.x));
    float wB = __expf(lrelu(an.y + ad.y));
    float2 hn = __half22float2(h2p[n * 64 + l]);
    float accA = wA * hn.x, accB = wB * hn.y;
    float denTA = wA, denTB = wB;
    float wsum = 0.f;

    int b = off[n];
    int deg = off[n + 1] - b;
    for (int base = 0; base < deg; base += 64) {
        int rem = deg - base;
        if (rem > 64) rem = 64;
        int sl = (l < rem) ? csr[b + base + l] : 0;
        int g = 0;
        for (; g + 8 <= rem; g += 8) {
            int sg = __shfl(sl, g + j8, 64);
            float w = __expf(lrelu(apf[sg * 8 + fidx] + dn));
            wsum += w;
#pragma unroll
            for (int j2 = 0; j2 < 8; ++j2) {
                int s = __builtin_amdgcn_readlane(sl, g + j2);
                float wa = __shfl(w, j2 * 8 + hA, 64);
                float wb = __shfl(w, j2 * 8 + hA + 4, 64);
                float2 gg = __half22float2(h2p[s * 64 + l]);
                accA = fmaf(wa, gg.x, accA);
                accB = fmaf(wb, gg.y, accB);
            }
        }
        if (g < rem) {
            int cnt2 = rem - g;
            int jj = (j8 < cnt2) ? j8 : 0;
            int sg = __shfl(sl, g + jj, 64);
            float w = (j8 < cnt2) ? __expf(lrelu(apf[sg * 8 + fidx] + dn)) : 0.f;
            wsum += w;
            for (int j2 = 0; j2 < cnt2; ++j2) {
                int s = __builtin_amdgcn_readlane(sl, g + j2);
                float wa = __shfl(w, j2 * 8 + hA, 64);
                float wb = __shfl(w, j2 * 8 + hA + 4, 64);
                float2 gg = __half22float2(h2p[s * 64 + l]);
                accA = fmaf(wa, gg.x, accA);
                accB = fmaf(wb, gg.y, accB);
            }
        }
    }
    wsum += __shfl_xor(wsum, 8, 64);
    wsum += __shfl_xor(wsum, 16, 64);
    wsum += __shfl_xor(wsum, 32, 64);
    float denA = denTA + __shfl(wsum, hA, 64);
    float denB = denTB + __shfl(wsum, hA + 4, 64);

    float v = accA / denA + accB / denB;
    v += __shfl_xor(v, 16, 64);
    v += __shfl_xor(v, 32, 64);
    v *= 0.125f;
    if (l < 16) smv[wid][l] = v;
    if (l == 0) smg[wid] = batch[n];
    __syncthreads();
    if (t < 64) {
        int w = t >> 4, c = t & 15;
        int g = smg[w];
        bool leader = true;
        for (int w2 = 0; w2 < w; ++w2)
            if (smg[w2] == g) { leader = false; break; }
        if (leader) {
            float s = smv[w][c];
            for (int w2 = w + 1; w2 < 4; ++w2)
                if (smg[w2] == g) s += smv[w2][c];
            atomicAdd(&pool[g * 16 + c], s);
        }
    }
}

// ---- final: pooled mean (+b2) @ Wfc + bfc -> [64,4]
__global__ void k_final(const float* __restrict__ pool, const int* __restrict__ cnt,
                        const float* __restrict__ b2, const float* __restrict__ Wfc,
                        const float* __restrict__ bfc, float* __restrict__ out) {
    int t = threadIdx.x;
    int g = t >> 2, k = t & 3;
    float c = (float)(cnt[g] > 0 ? cnt[g] : 1);
    float acc = bfc[k];
#pragma unroll
    for (int ci = 0; ci < 16; ++ci)
        acc += (pool[g * 16 + ci] / c + b2[ci]) * Wfc[ci * 4 + k];
    out[g * 4 + k] = acc;
}

extern "C" void kernel_launch(void* const* d_in, const int* in_sizes, int n_in,
                              void* d_out, int out_size, void* d_ws, size_t ws_size,
                              hipStream_t stream) {
    const float* x   = (const float*)d_in[0];
    const float* W1  = (const float*)d_in[1];
    const float* as1 = (const float*)d_in[2];
    const float* ad1 = (const float*)d_in[3];
    const float* b1  = (const float*)d_in[4];
    const float* W2  = (const float*)d_in[5];
    const float* as2 = (const float*)d_in[6];
    const float* ad2 = (const float*)d_in[7];
    const float* b2  = (const float*)d_in[8];
    const float* Wfc = (const float*)d_in[9];
    const float* bfc = (const float*)d_in[10];
    const int* ei    = (const int*)d_in[11];
    const int* batch = (const int*)d_in[12];
    const int* srcv  = ei;             // edge_index[0]
    const int* dstv  = ei + N_EDGES;   // edge_index[1]

    char* ws = (char*)d_ws;
    size_t o = 0;
    auto alloc = [&](size_t bytes) {
        void* p = ws + o;
        o += (bytes + 255) & ~(size_t)255;
        return p;
    };
    // zero-region first (one memset): cnt, pool, gbin_cursor
    int*    cnt     = (int*)alloc(64 * 4);
    float*  pool    = (float*)alloc(64 * 16 * 4);
    int*    gbin    = (int*)alloc(NBIN * 4);
    size_t  zbytes  = o;
    int*    off     = (int*)alloc((size_t)(N_NODES + 1) * 4);
    int*    csr     = (int*)alloc((size_t)N_EDGES * 4);
    float2* ap      = (float2*)alloc((size_t)N_NODES * 4 * 8);
    float2* dp      = (float2*)alloc((size_t)N_NODES * 4 * 8);
    int*    binned  = (int*)alloc((size_t)NBIN * BINCAP * 4);    // 8.0 MB packed
    __half2* h2p    = (__half2*)alloc((size_t)N_NODES * 64 * 4); // 25.6 MB

    hipMemsetAsync(d_ws, 0, zbytes, stream);

    int nbA = (N_EDGES + EPB - 1) / EPB;   // 391

    k_binA<<<nbA, 1024, 0, stream>>>(srcv, dstv, batch, gbin, cnt, binned);
    k_megaB<<<NBIN, 1024, 0, stream>>>(binned, gbin, off, csr,
                                       x, W1, as1, ad1, b1, W2, as2, ad2,
                                       h2p, ap, dp);
    k_layer2<<<N_NODES / 4, 256, 0, stream>>>(h2p, ap, dp, off, csr, batch, pool);
    k_final<<<1, 256, 0, stream>>>(pool, cnt, b2, Wfc, bfc, (float*)d_out);
}